// Round 5
// baseline (186.517 us; speedup 1.0000x reference)
//
#include <hip/hip_runtime.h>
#include <hip/hip_bf16.h>

// RUDY routing-demand maps via difference-domain + 2D prefix sum.
// Each net deposits wt * u(x) ⊗ v(y); the first difference of the bin-overlap
// profile u has <=4 nonzeros (at i0,i0+1,i1,i1+1), so each net contributes
// <=16 difference-grid cells; one inclusive scan per dimension reconstructs
// the maps.
//
// Round-5 change: rounds 2-4 proved global f32 atomics execute at the
// memory-side coherence point (WRITE_SIZE == 96 MB == 3.07M atomics x 32 B,
// invariant under 16-way replication AND workgroup-scope), capping the old
// scatter at ~18 G atomics/s with all pipes idle. This version has ZERO
// global atomics: pass 1 writes per-net records; pass 2 gives each x-row to
// one block (exclusive ownership), which scans the compact u16 key array,
// queues matching nets in LDS, deposits with LDS atomics, y-scans in LDS,
// and writes its row non-atomically.

#define NBX 256
#define NBY 256
#define NMAP (NBX * NBY)
#define TILE 8192   // nets per scan tile; queue can never overflow (<= TILE)

constexpr float BSX = 2.0f;
constexpr float BSY = 2.0f;
// 1/(bin_area * UNIT_HCAP), 1/(bin_area * UNIT_VCAP)
constexpr float INV_H = 1.0f / (4.0f * 50.0f);
constexpr float INV_V = 1.0f / (4.0f * 40.0f);

// Cumulative overlap length of [mn,mx] with [0, t].
__device__ __forceinline__ float seg_cum(float t, float mn, float mx) {
    return fminf(fmaxf(t, mn), mx) - mn;
}

// First difference of the per-bin overlap U(i) of [mn,mx] with bin i.
__device__ __forceinline__ float second_diff(int i, float bs, float mn, float mx) {
    float u2 = seg_cum((float)(i + 1) * bs, mn, mx);
    float u1 = seg_cum((float)(i) * bs, mn, mx);
    float u0 = seg_cum((float)(i - 1) * bs, mn, mx);
    return (u2 - u1) - (u1 - u0);
}

// Pass 1: per-net bbox -> SoA records + compact x-breakpoint key.
__global__ void __launch_bounds__(256) net_bbox(
    const float* __restrict__ pin_pos,
    const int* __restrict__ netpin_start,
    const int* __restrict__ flat_netpin,
    const float* __restrict__ net_weights,
    float4* __restrict__ bbox4,          // {xmn,xmx,ymn,ymx}
    float2* __restrict__ wt2,            // {wh, wv}
    unsigned short* __restrict__ key,    // i0 | (i1<<8)
    int num_nets) {
    int n = blockIdx.x * 256 + threadIdx.x;
    if (n >= num_nets) return;
    int s = netpin_start[n];
    int e = netpin_start[n + 1];
    if (e <= s) {  // degenerate: all-zero record (deposits vanish)
        bbox4[n] = make_float4(0.f, 0.f, 0.f, 0.f);
        wt2[n]   = make_float2(0.f, 0.f);
        key[n]   = 0;
        return;
    }
    float xmn = 3.0e38f, xmx = -3.0e38f, ymn = 3.0e38f, ymx = -3.0e38f;
    for (int p = s; p < e; ++p) {
        int ip = flat_netpin[p];
        float2 xy = *reinterpret_cast<const float2*>(pin_pos + 2 * (size_t)ip);
        xmn = fminf(xmn, xy.x);
        xmx = fmaxf(xmx, xy.x);
        ymn = fminf(ymn, xy.y);
        ymx = fmaxf(ymx, xy.y);
    }
    float w = net_weights[n];
    bbox4[n] = make_float4(xmn, xmx, ymn, ymx);
    wt2[n]   = make_float2(w / (ymx - ymn), w / (xmx - xmn));
    int i0 = (int)floorf(xmn * 0.5f);
    int i1 = (int)floorf(xmx * 0.5f);
    key[n] = (unsigned short)((i0 & 255) | ((i1 & 255) << 8));
}

// Pass 2: one block per x-row. Scan keys -> LDS queue -> dense deposit into
// LDS row accumulator (LDS atomics) -> in-LDS y-scan -> write row.
__global__ void __launch_bounds__(256) row_build(
    const float4* __restrict__ bbox4,
    const float2* __restrict__ wt2,
    const unsigned short* __restrict__ key,
    float2* __restrict__ D,
    int num_nets) {
    __shared__ float row_h[NBY];
    __shared__ float row_v[NBY];
    __shared__ int   queue[TILE];
    __shared__ int   qcnt;

    const int r   = blockIdx.x;
    const int tid = threadIdx.x;

    row_h[tid] = 0.0f;
    row_v[tid] = 0.0f;
    if (tid == 0) qcnt = 0;
    __syncthreads();

    for (int t0 = 0; t0 < num_nets; t0 += TILE) {
        int tend = min(t0 + TILE, num_nets);
        // Phase A: compact matching nets into the queue.
        for (int i = t0 + tid; i < tend; i += 256) {
            int k  = key[i];
            int i0 = k & 255;
            int i1 = k >> 8;
            if (r == i0 || r == i0 + 1 || r == i1 || r == i1 + 1) {
                queue[atomicAdd(&qcnt, 1)] = i;
            }
        }
        __syncthreads();
        // Phase B: dense deposit.
        int qn = qcnt;
        for (int q = tid; q < qn; q += 256) {
            int n = queue[q];
            float4 bb = bbox4[n];
            float2 wt = wt2[n];
            float dxr = second_diff(r, BSX, bb.x, bb.y);
            if (dxr != 0.0f) {
                int j0 = (int)floorf(bb.z * 0.5f);
                int j1 = (int)floorf(bb.w * 0.5f);
                int yi[4];
                yi[0] = j0;
                yi[1] = j0 + 1;
                yi[2] = (j1 > j0 + 1) ? j1 : -1;      // dedup when bboxes overlap
                yi[3] = (j1 > j0) ? j1 + 1 : -1;
                float hh = wt.x * dxr;
                float vv = wt.y * dxr;
#pragma unroll
                for (int c = 0; c < 4; ++c) {
                    if (yi[c] >= 0 && yi[c] < NBY) {
                        float dy = second_diff(yi[c], BSY, bb.z, bb.w);
                        if (dy != 0.0f) {
                            atomicAdd(&row_h[yi[c]], hh * dy);
                            atomicAdd(&row_v[yi[c]], vv * dy);
                        }
                    }
                }
            }
        }
        __syncthreads();
        if (tid == 0) qcnt = 0;
        __syncthreads();
    }

    // Inclusive y-scan (Hillis-Steele) of the finished difference row.
    for (int off = 1; off < NBY; off <<= 1) {
        float ah = (tid >= off) ? row_h[tid - off] : 0.0f;
        float av = (tid >= off) ? row_v[tid - off] : 0.0f;
        __syncthreads();
        row_h[tid] += ah;
        row_v[tid] += av;
        __syncthreads();
    }
    D[r * NBY + tid] = make_float2(row_h[tid], row_v[tid]);
}

// Pass 3: inclusive scan along x per column (one block per y) + finalize.
__global__ void __launch_bounds__(256) scan_cols_finalize(
    const float2* __restrict__ D,
    const float* __restrict__ init_h,
    const float* __restrict__ init_v,
    float* __restrict__ out) {
    __shared__ float bh[NBX];
    __shared__ float bv[NBX];
    int y = blockIdx.x;
    int x = threadIdx.x;
    float2 t = D[x * NBY + y];
    bh[x] = t.x;
    bv[x] = t.y;
    __syncthreads();
    for (int off = 1; off < NBX; off <<= 1) {
        float ah = (x >= off) ? bh[x - off] : 0.0f;
        float av = (x >= off) ? bv[x - off] : 0.0f;
        __syncthreads();
        bh[x] += ah;
        bv[x] += av;
        __syncthreads();
    }
    int idx = x * NBY + y;
    float H = fmaf(bh[x], INV_H, init_h[idx]);
    float V = fmaf(bv[x], INV_V, init_v[idx]);
    float r = fmaxf(fabsf(H), fabsf(V));
    out[idx]            = r;
    out[idx + NMAP]     = H;
    out[idx + 2 * NMAP] = V;
}

extern "C" void kernel_launch(void* const* d_in, const int* in_sizes, int n_in,
                              void* d_out, int out_size, void* d_ws, size_t ws_size,
                              hipStream_t stream) {
    const float* pin_pos      = (const float*)d_in[0];
    const int*   netpin_start = (const int*)d_in[1];
    const int*   flat_netpin  = (const int*)d_in[2];
    const float* net_weights  = (const float*)d_in[3];
    const float* init_h       = (const float*)d_in[4];
    const float* init_v       = (const float*)d_in[5];
    float* out = (float*)d_out;

    int num_nets = in_sizes[3];                      // net_weights length
    size_t Np = ((size_t)num_nets + 255) & ~(size_t)255;

    // ws layout (all regions fully written before read; no memset needed):
    // [bbox4: Np*16][wt2: Np*8][key: Np*2][D: NMAP*8]  ~= 3.1 MB at 100k nets
    char* w = (char*)d_ws;
    float4*         bbox4 = (float4*)(w);
    float2*         wt2   = (float2*)(w + Np * 16);
    unsigned short* key   = (unsigned short*)(w + Np * 24);
    float2*         D     = (float2*)(w + Np * 26);

    int blocks = (num_nets + 255) / 256;
    net_bbox<<<blocks, 256, 0, stream>>>(pin_pos, netpin_start, flat_netpin,
                                         net_weights, bbox4, wt2, key, num_nets);
    row_build<<<NBX, 256, 0, stream>>>(bbox4, wt2, key, D, num_nets);
    scan_cols_finalize<<<NBY, 256, 0, stream>>>(D, init_h, init_v, out);
}

// Round 6
// 113.472 us; speedup vs baseline: 1.6437x; 1.6437x over previous
//
#include <hip/hip_runtime.h>
#include <hip/hip_bf16.h>

// RUDY routing-demand maps via difference-domain + 2D prefix sum.
// Each net deposits wt * u(x) ⊗ v(y); the first difference of the bin-overlap
// profile u has <=4 nonzeros (rows i0,i0+1,i1,i1+1), so each net contributes
// <=16 difference-grid cells; one inclusive scan per dimension reconstructs
// the maps.
//
// Round-6 change: round-5's row_build was serialized-latency-bound (169 us,
// VALU 6%, HBM 0.8%: 416 scalar u16 key loads/thread, each exposed at full
// L2 latency because the divergent LDS-atomic body blocks pipelining).
// Fix: (1) uint4 key loads (8 keys/load), (2) 8 slices per row (grid 2048,
// 8 blocks/CU, partial rows folded in the scan pass), (3) inline deposit,
// no queue (LDS 35 KB -> 2 KB). Zero global atomics throughout.

#define NBX 256
#define NBY 256
#define NMAP (NBX * NBY)
#define MAXS 8

constexpr float BSX = 2.0f;
constexpr float BSY = 2.0f;
// 1/(bin_area * UNIT_HCAP), 1/(bin_area * UNIT_VCAP)
constexpr float INV_H = 1.0f / (4.0f * 50.0f);
constexpr float INV_V = 1.0f / (4.0f * 40.0f);

// Cumulative overlap length of [mn,mx] with [0, t].
__device__ __forceinline__ float seg_cum(float t, float mn, float mx) {
    return fminf(fmaxf(t, mn), mx) - mn;
}

// First difference of the per-bin overlap U(i) of [mn,mx] with bin i.
__device__ __forceinline__ float second_diff(int i, float bs, float mn, float mx) {
    float u2 = seg_cum((float)(i + 1) * bs, mn, mx);
    float u1 = seg_cum((float)(i) * bs, mn, mx);
    float u0 = seg_cum((float)(i - 1) * bs, mn, mx);
    return (u2 - u1) - (u1 - u0);
}

// Pass 1: per-net bbox -> SoA records + compact x-breakpoint key.
// Covers the padded range [0, Np) so the vectorized key scan never reads
// uninitialized memory.
__global__ void __launch_bounds__(256) net_bbox(
    const float* __restrict__ pin_pos,
    const int* __restrict__ netpin_start,
    const int* __restrict__ flat_netpin,
    const float* __restrict__ net_weights,
    float4* __restrict__ bbox4,          // {xmn,xmx,ymn,ymx}
    float2* __restrict__ wt2,            // {wh, wv}
    unsigned short* __restrict__ key,    // i0 | (i1<<8)
    int num_nets, int Np) {
    int n = blockIdx.x * 256 + threadIdx.x;
    if (n >= Np) return;
    int s = 0, e = 0;
    if (n < num_nets) {
        s = netpin_start[n];
        e = netpin_start[n + 1];
    }
    if (e <= s) {  // padding or degenerate: zero record (never deposits)
        bbox4[n] = make_float4(0.f, 0.f, 0.f, 0.f);
        wt2[n]   = make_float2(0.f, 0.f);
        key[n]   = 0;
        return;
    }
    float xmn = 3.0e38f, xmx = -3.0e38f, ymn = 3.0e38f, ymx = -3.0e38f;
    if (e - s == 8 && (s & 3) == 0) {   // common case: 8 pins, aligned
        int4 a = *reinterpret_cast<const int4*>(flat_netpin + s);
        int4 b = *reinterpret_cast<const int4*>(flat_netpin + s + 4);
        int idx[8] = {a.x, a.y, a.z, a.w, b.x, b.y, b.z, b.w};
#pragma unroll
        for (int p = 0; p < 8; ++p) {
            float2 xy = *reinterpret_cast<const float2*>(pin_pos + 2 * (size_t)idx[p]);
            xmn = fminf(xmn, xy.x);
            xmx = fmaxf(xmx, xy.x);
            ymn = fminf(ymn, xy.y);
            ymx = fmaxf(ymx, xy.y);
        }
    } else {
        for (int p = s; p < e; ++p) {
            int ip = flat_netpin[p];
            float2 xy = *reinterpret_cast<const float2*>(pin_pos + 2 * (size_t)ip);
            xmn = fminf(xmn, xy.x);
            xmx = fmaxf(xmx, xy.x);
            ymn = fminf(ymn, xy.y);
            ymx = fmaxf(ymx, xy.y);
        }
    }
    float w = net_weights[n];
    bbox4[n] = make_float4(xmn, xmx, ymn, ymx);
    wt2[n]   = make_float2(w / (ymx - ymn), w / (xmx - xmn));
    int i0 = (int)floorf(xmn * 0.5f);
    int i1 = (int)floorf(xmx * 0.5f);
    key[n] = (unsigned short)((i0 & 255) | ((i1 & 255) << 8));
}

// Pass 2: block (slice, r) scans its key chunk with uint4 loads and deposits
// matching nets inline into a 2 KB LDS partial row; writes Dpart[slice].
__global__ void __launch_bounds__(256) row_build_partial(
    const float4* __restrict__ bbox4,
    const float2* __restrict__ wt2,
    const uint4* __restrict__ key4,      // 8 keys per element
    float2* __restrict__ Dpart,
    int Np, int chunk8, int S) {
    __shared__ float row_h[NBY];
    __shared__ float row_v[NBY];
    const int r     = blockIdx.x & (NBX - 1);
    const int slice = blockIdx.x >> 8;
    const int tid   = threadIdx.x;

    row_h[tid] = 0.0f;
    row_v[tid] = 0.0f;
    __syncthreads();

    auto deposit = [&](int n) {
        float4 bb = bbox4[n];
        float dxr = second_diff(r, BSX, bb.x, bb.y);
        if (dxr == 0.0f) return;
        float2 wt = wt2[n];
        float hh = wt.x * dxr;
        float vv = wt.y * dxr;
        int j0 = (int)floorf(bb.z * 0.5f);
        int j1 = (int)floorf(bb.w * 0.5f);
        int yi[4];
        yi[0] = j0;
        yi[1] = j0 + 1;
        yi[2] = (j1 > j0 + 1) ? j1 : -1;     // dedup overlapping candidates
        yi[3] = (j1 > j0) ? j1 + 1 : -1;
#pragma unroll
        for (int c = 0; c < 4; ++c) {
            int y = yi[c];
            if (y >= 0 && y < NBY) {
                float dy = second_diff(y, BSY, bb.z, bb.w);
                if (dy != 0.0f) {
                    atomicAdd(&row_h[y], hh * dy);
                    atomicAdd(&row_v[y], vv * dy);
                }
            }
        }
    };

    int ibeg = slice * chunk8;
    int iend = min(ibeg + chunk8, Np >> 3);
    for (int i = ibeg + tid; i < iend; i += 256) {
        uint4 kv = key4[i];
        int base = i << 3;
        unsigned wl[4] = {kv.x, kv.y, kv.z, kv.w};
#pragma unroll
        for (int q = 0; q < 4; ++q) {
#pragma unroll
            for (int h = 0; h < 2; ++h) {
                unsigned k = (wl[q] >> (16 * h)) & 0xFFFFu;
                int ia = (int)(k & 255u);
                int ib = (int)((k >> 8) & 255u);
                if ((unsigned)(r - ia) <= 1u || (unsigned)(r - ib) <= 1u)
                    deposit(base + 2 * q + h);
            }
        }
    }
    __syncthreads();
    Dpart[(size_t)slice * NMAP + r * NBY + tid] = make_float2(row_h[tid], row_v[tid]);
}

// Pass 3: fold S partial slices + inclusive y-scan; result -> slice 0.
__global__ void __launch_bounds__(256) scan_rows_fold(float2* __restrict__ Dpart, int S) {
    __shared__ float bh[NBY];
    __shared__ float bv[NBY];
    int r = blockIdx.x;
    int y = threadIdx.x;
    float h = 0.0f, v = 0.0f;
    for (int s = 0; s < S; ++s) {
        float2 t = Dpart[(size_t)s * NMAP + r * NBY + y];
        h += t.x;
        v += t.y;
    }
    bh[y] = h;
    bv[y] = v;
    __syncthreads();
    for (int off = 1; off < NBY; off <<= 1) {
        float ah = (y >= off) ? bh[y - off] : 0.0f;
        float av = (y >= off) ? bv[y - off] : 0.0f;
        __syncthreads();
        bh[y] += ah;
        bv[y] += av;
        __syncthreads();
    }
    Dpart[r * NBY + y] = make_float2(bh[y], bv[y]);   // safe: writes own read slot
}

// Pass 4: inclusive scan along x per column (one block per y) + finalize.
__global__ void __launch_bounds__(256) scan_cols_finalize(
    const float2* __restrict__ D,
    const float* __restrict__ init_h,
    const float* __restrict__ init_v,
    float* __restrict__ out) {
    __shared__ float bh[NBX];
    __shared__ float bv[NBX];
    int y = blockIdx.x;
    int x = threadIdx.x;
    float2 t = D[x * NBY + y];
    bh[x] = t.x;
    bv[x] = t.y;
    __syncthreads();
    for (int off = 1; off < NBX; off <<= 1) {
        float ah = (x >= off) ? bh[x - off] : 0.0f;
        float av = (x >= off) ? bv[x - off] : 0.0f;
        __syncthreads();
        bh[x] += ah;
        bv[x] += av;
        __syncthreads();
    }
    int idx = x * NBY + y;
    float H = fmaf(bh[x], INV_H, init_h[idx]);
    float V = fmaf(bv[x], INV_V, init_v[idx]);
    float r = fmaxf(fabsf(H), fabsf(V));
    out[idx]            = r;
    out[idx + NMAP]     = H;
    out[idx + 2 * NMAP] = V;
}

extern "C" void kernel_launch(void* const* d_in, const int* in_sizes, int n_in,
                              void* d_out, int out_size, void* d_ws, size_t ws_size,
                              hipStream_t stream) {
    const float* pin_pos      = (const float*)d_in[0];
    const int*   netpin_start = (const int*)d_in[1];
    const int*   flat_netpin  = (const int*)d_in[2];
    const float* net_weights  = (const float*)d_in[3];
    const float* init_h       = (const float*)d_in[4];
    const float* init_v       = (const float*)d_in[5];
    float* out = (float*)d_out;

    int num_nets = in_sizes[3];                       // net_weights length
    int Np = (num_nets + 255) & ~255;                 // padded net count

    // ws layout (all regions fully written before read; no memset needed):
    // [bbox4: Np*16][wt2: Np*8][key: Np*2][Dpart: S*NMAP*8]
    char* w = (char*)d_ws;
    float4*         bbox4 = (float4*)(w);
    float2*         wt2   = (float2*)(w + (size_t)Np * 16);
    unsigned short* key   = (unsigned short*)(w + (size_t)Np * 24);
    float2*         Dpart = (float2*)(w + (size_t)Np * 26);  // 16B-aligned (Np%256==0)

    size_t avail = ws_size - (size_t)Np * 26;
    int S = (int)(avail / ((size_t)NMAP * sizeof(float2)));
    if (S > MAXS) S = MAXS;
    if (S < 1) S = 1;
    int n4 = Np >> 3;                                 // total uint4 key elements
    int chunk8 = (n4 + S - 1) / S;

    net_bbox<<<Np / 256, 256, 0, stream>>>(pin_pos, netpin_start, flat_netpin,
                                           net_weights, bbox4, wt2, key,
                                           num_nets, Np);
    row_build_partial<<<NBX * S, 256, 0, stream>>>(bbox4, wt2, (const uint4*)key,
                                                   Dpart, Np, chunk8, S);
    scan_rows_fold<<<NBX, 256, 0, stream>>>(Dpart, S);
    scan_cols_finalize<<<NBY, 256, 0, stream>>>(Dpart, init_h, init_v, out);
}

// Round 7
// 105.391 us; speedup vs baseline: 1.7698x; 1.0767x over previous
//
#include <hip/hip_runtime.h>
#include <hip/hip_bf16.h>

// RUDY routing-demand maps via difference-domain + 2D prefix sum.
// Each net deposits wt * u(x) ⊗ v(y); the first difference of the bin-overlap
// profile u has <=4 nonzeros (rows i0,i0+1,i1,i1+1), so each net contributes
// <=16 difference-grid cells; one inclusive scan per dimension reconstructs
// the maps. Zero global atomics (rounds 2-4: global f32 atomics are
// memory-side, ~18 G/s wall regardless of scope/replication).
//
// Round-7 change: round-6 row_build was divergence-bound (92 us, VALU 41%:
// ~5 one-active-lane deposit bodies per wave-iteration, each gated on a
// random L2 bbox load). Fix: per-tile LDS queue compaction (Phase A: scan
// keys, push matches; Phase B: all lanes process consecutive queue entries
// -> ~100% lane utilization, batched L2 loads). net_bbox: 8 lanes per net +
// __shfl_xor butterfly (800k threads, full TLP) instead of 8 serial loads.

#define NBX 256
#define NBY 256
#define NMAP (NBX * NBY)
#define MAXS 8
#define TILEK 4096   // keys per scan tile == queue capacity (cannot overflow)

constexpr float BSX = 2.0f;
constexpr float BSY = 2.0f;
// 1/(bin_area * UNIT_HCAP), 1/(bin_area * UNIT_VCAP)
constexpr float INV_H = 1.0f / (4.0f * 50.0f);
constexpr float INV_V = 1.0f / (4.0f * 40.0f);

// Cumulative overlap length of [mn,mx] with [0, t].
__device__ __forceinline__ float seg_cum(float t, float mn, float mx) {
    return fminf(fmaxf(t, mn), mx) - mn;
}

// First difference of the per-bin overlap U(i) of [mn,mx] with bin i.
__device__ __forceinline__ float second_diff(int i, float bs, float mn, float mx) {
    float u2 = seg_cum((float)(i + 1) * bs, mn, mx);
    float u1 = seg_cum((float)(i) * bs, mn, mx);
    float u0 = seg_cum((float)(i - 1) * bs, mn, mx);
    return (u2 - u1) - (u1 - u0);
}

// Pass 1: 8 lanes per net; each lane loads its pin(s), 3-step shfl butterfly
// reduces min/max, lane 0 writes the record. Covers padded [0, Np).
__global__ void __launch_bounds__(256) net_bbox(
    const float* __restrict__ pin_pos,
    const int* __restrict__ netpin_start,
    const int* __restrict__ flat_netpin,
    const float* __restrict__ net_weights,
    float4* __restrict__ bbox4,          // {xmn,xmx,ymn,ymx}
    float2* __restrict__ wt2,            // {wh, wv}
    unsigned short* __restrict__ key,    // i0 | (i1<<8)
    int num_nets, int Np) {
    int n = blockIdx.x * 32 + (threadIdx.x >> 3);   // net id (8 lanes each)
    int l = threadIdx.x & 7;
    if (n >= Np) return;
    int s = 0, e = 0;
    if (n < num_nets) {
        s = netpin_start[n];
        e = netpin_start[n + 1];
    }
    float xmn = 3.0e38f, xmx = -3.0e38f, ymn = 3.0e38f, ymx = -3.0e38f;
    for (int p = s + l; p < e; p += 8) {
        int ip = flat_netpin[p];
        float2 xy = *reinterpret_cast<const float2*>(pin_pos + 2 * (size_t)ip);
        xmn = fminf(xmn, xy.x);
        xmx = fmaxf(xmx, xy.x);
        ymn = fminf(ymn, xy.y);
        ymx = fmaxf(ymx, xy.y);
    }
#pragma unroll
    for (int m = 1; m < 8; m <<= 1) {    // 8-lane group butterfly
        xmn = fminf(xmn, __shfl_xor(xmn, m));
        xmx = fmaxf(xmx, __shfl_xor(xmx, m));
        ymn = fminf(ymn, __shfl_xor(ymn, m));
        ymx = fmaxf(ymx, __shfl_xor(ymx, m));
    }
    if (l == 0) {
        if (e <= s) {                    // padding / degenerate net
            bbox4[n] = make_float4(0.f, 0.f, 0.f, 0.f);
            wt2[n]   = make_float2(0.f, 0.f);
            key[n]   = 0;
        } else {
            float w = net_weights[n];
            bbox4[n] = make_float4(xmn, xmx, ymn, ymx);
            wt2[n]   = make_float2(w / (ymx - ymn), w / (xmx - xmn));
            int i0 = (int)floorf(xmn * 0.5f);
            int i1 = (int)floorf(xmx * 0.5f);
            key[n] = (unsigned short)((i0 & 255) | ((i1 & 255) << 8));
        }
    }
}

// Pass 2: block (slice, r). Per 4096-key tile: Phase A scans keys (uint4,
// 8 keys/load) and compacts matching net ids into an LDS queue; Phase B
// processes the queue densely (all lanes, consecutive entries). Then in-LDS
// y-scan is deferred to the fold pass; here we just write the partial row.
__global__ void __launch_bounds__(256) row_build_partial(
    const float4* __restrict__ bbox4,
    const float2* __restrict__ wt2,
    const uint4* __restrict__ key4,      // 8 keys per element
    float2* __restrict__ Dpart,
    int Np, int chunk8, int S) {
    __shared__ float row_h[NBY];
    __shared__ float row_v[NBY];
    __shared__ int   queue[TILEK];
    __shared__ int   qcnt;
    const int r     = blockIdx.x & (NBX - 1);
    const int slice = blockIdx.x >> 8;
    const int tid   = threadIdx.x;

    row_h[tid] = 0.0f;
    row_v[tid] = 0.0f;
    if (tid == 0) qcnt = 0;
    __syncthreads();

    const int n4   = Np >> 3;
    const int ibeg = slice * chunk8;
    const int iend = min(ibeg + chunk8, n4);

    for (int t0 = ibeg; t0 < iend; t0 += (TILEK >> 3)) {
        int t1 = min(t0 + (TILEK >> 3), iend);
        // Phase A: compact matching nets into the queue.
        for (int i = t0 + tid; i < t1; i += 256) {
            uint4 kv = key4[i];
            int base = i << 3;
            unsigned wl[4] = {kv.x, kv.y, kv.z, kv.w};
#pragma unroll
            for (int q = 0; q < 4; ++q) {
#pragma unroll
                for (int h = 0; h < 2; ++h) {
                    unsigned k = (wl[q] >> (16 * h)) & 0xFFFFu;
                    int ia = (int)(k & 255u);
                    int ib = (int)((k >> 8) & 255u);
                    if ((unsigned)(r - ia) <= 1u || (unsigned)(r - ib) <= 1u)
                        queue[atomicAdd(&qcnt, 1)] = base + 2 * q + h;
                }
            }
        }
        __syncthreads();
        // Phase B: dense deposit — every lane one queue entry.
        int qn = qcnt;
        for (int q = tid; q < qn; q += 256) {
            int n = queue[q];
            float4 bb = bbox4[n];
            float dxr = second_diff(r, BSX, bb.x, bb.y);
            if (dxr != 0.0f) {
                float2 wt = wt2[n];
                float hh = wt.x * dxr;
                float vv = wt.y * dxr;
                int j0 = (int)floorf(bb.z * 0.5f);
                int j1 = (int)floorf(bb.w * 0.5f);
                int yi[4];
                yi[0] = j0;
                yi[1] = j0 + 1;
                yi[2] = (j1 > j0 + 1) ? j1 : -1;   // dedup overlapping cands
                yi[3] = (j1 > j0) ? j1 + 1 : -1;
#pragma unroll
                for (int c = 0; c < 4; ++c) {
                    int y = yi[c];
                    if (y >= 0 && y < NBY) {
                        float dy = second_diff(y, BSY, bb.z, bb.w);
                        if (dy != 0.0f) {
                            atomicAdd(&row_h[y], hh * dy);
                            atomicAdd(&row_v[y], vv * dy);
                        }
                    }
                }
            }
        }
        __syncthreads();
        if (tid == 0) qcnt = 0;
        __syncthreads();
    }
    Dpart[(size_t)slice * NMAP + r * NBY + tid] = make_float2(row_h[tid], row_v[tid]);
}

// Pass 3: fold S partial slices + inclusive y-scan; result -> slice 0.
__global__ void __launch_bounds__(256) scan_rows_fold(float2* __restrict__ Dpart, int S) {
    __shared__ float bh[NBY];
    __shared__ float bv[NBY];
    int r = blockIdx.x;
    int y = threadIdx.x;
    float h = 0.0f, v = 0.0f;
    for (int s = 0; s < S; ++s) {
        float2 t = Dpart[(size_t)s * NMAP + r * NBY + y];
        h += t.x;
        v += t.y;
    }
    bh[y] = h;
    bv[y] = v;
    __syncthreads();
    for (int off = 1; off < NBY; off <<= 1) {
        float ah = (y >= off) ? bh[y - off] : 0.0f;
        float av = (y >= off) ? bv[y - off] : 0.0f;
        __syncthreads();
        bh[y] += ah;
        bv[y] += av;
        __syncthreads();
    }
    Dpart[r * NBY + y] = make_float2(bh[y], bv[y]);   // writes own read slot
}

// Pass 4: inclusive scan along x per column (one block per y) + finalize.
__global__ void __launch_bounds__(256) scan_cols_finalize(
    const float2* __restrict__ D,
    const float* __restrict__ init_h,
    const float* __restrict__ init_v,
    float* __restrict__ out) {
    __shared__ float bh[NBX];
    __shared__ float bv[NBX];
    int y = blockIdx.x;
    int x = threadIdx.x;
    float2 t = D[x * NBY + y];
    bh[x] = t.x;
    bv[x] = t.y;
    __syncthreads();
    for (int off = 1; off < NBX; off <<= 1) {
        float ah = (x >= off) ? bh[x - off] : 0.0f;
        float av = (x >= off) ? bv[x - off] : 0.0f;
        __syncthreads();
        bh[x] += ah;
        bv[x] += av;
        __syncthreads();
    }
    int idx = x * NBY + y;
    float H = fmaf(bh[x], INV_H, init_h[idx]);
    float V = fmaf(bv[x], INV_V, init_v[idx]);
    float r = fmaxf(fabsf(H), fabsf(V));
    out[idx]            = r;
    out[idx + NMAP]     = H;
    out[idx + 2 * NMAP] = V;
}

extern "C" void kernel_launch(void* const* d_in, const int* in_sizes, int n_in,
                              void* d_out, int out_size, void* d_ws, size_t ws_size,
                              hipStream_t stream) {
    const float* pin_pos      = (const float*)d_in[0];
    const int*   netpin_start = (const int*)d_in[1];
    const int*   flat_netpin  = (const int*)d_in[2];
    const float* net_weights  = (const float*)d_in[3];
    const float* init_h       = (const float*)d_in[4];
    const float* init_v       = (const float*)d_in[5];
    float* out = (float*)d_out;

    int num_nets = in_sizes[3];                       // net_weights length
    int Np = (num_nets + 255) & ~255;                 // padded net count

    // ws layout (all regions fully written before read; no memset needed):
    // [bbox4: Np*16][wt2: Np*8][key: Np*2][Dpart: S*NMAP*8]
    char* w = (char*)d_ws;
    float4*         bbox4 = (float4*)(w);
    float2*         wt2   = (float2*)(w + (size_t)Np * 16);
    unsigned short* key   = (unsigned short*)(w + (size_t)Np * 24);
    float2*         Dpart = (float2*)(w + (size_t)Np * 26);  // 16B-aligned

    size_t avail = ws_size - (size_t)Np * 26;
    int S = (int)(avail / ((size_t)NMAP * sizeof(float2)));
    if (S > MAXS) S = MAXS;
    if (S < 1) S = 1;
    int n4 = Np >> 3;                                 // total uint4 key elements
    int chunk8 = (n4 + S - 1) / S;

    net_bbox<<<Np / 32, 256, 0, stream>>>(pin_pos, netpin_start, flat_netpin,
                                          net_weights, bbox4, wt2, key,
                                          num_nets, Np);
    row_build_partial<<<NBX * S, 256, 0, stream>>>(bbox4, wt2, (const uint4*)key,
                                                   Dpart, Np, chunk8, S);
    scan_rows_fold<<<NBX, 256, 0, stream>>>(Dpart, S);
    scan_cols_finalize<<<NBY, 256, 0, stream>>>(Dpart, init_h, init_v, out);
}

// Round 8
// 98.154 us; speedup vs baseline: 1.9002x; 1.0737x over previous
//
#include <hip/hip_runtime.h>
#include <hip/hip_bf16.h>

// RUDY routing-demand maps via difference-domain + 2D prefix sum.
// Each net deposits wt * u(x) ⊗ v(y); the first difference of the bin-overlap
// profile u has <=4 nonzeros (rows i0,i0+1,i1,i1+1), so each net contributes
// <=16 difference-grid cells; one inclusive scan per dimension reconstructs
// the maps.
//
// Round-8 change: rounds 6-7 shared a ~75 us floor in the row-scan structure
// (2048 blocks x full key array = 25.6M redundant tests; floor survived two
// different inner loops -> structural). Replace broadcast-scan with binning:
// nets are scattered once into 128 row-PAIR buckets (<=4 pairs/net, ~3 avg;
// per-block LDS histogram + one global atomicAdd reservation per (block,pair)
// = ~50k global atomics ~ 3 us of the measured 18 G/s atomic pipe). Each
// row-pair block then processes only its own bucket: dense, barrier-free,
// LDS-atomic deposits. Zero per-cell global atomics throughout.

#define NBX 256
#define NBY 256
#define NMAP (NBX * NBY)
#define NPAIR 128           // row pairs: pair p owns rows {2p, 2p+1}
#define SLICES 2            // bucket split for straggler smoothing
#define CAPMAX 8192         // bucket capacity (expected max ~6100 +- 85)

constexpr float BSX = 2.0f;
constexpr float BSY = 2.0f;
// 1/(bin_area * UNIT_HCAP), 1/(bin_area * UNIT_VCAP)
constexpr float INV_H = 1.0f / (4.0f * 50.0f);
constexpr float INV_V = 1.0f / (4.0f * 40.0f);

// Cumulative overlap length of [mn,mx] with [0, t].
__device__ __forceinline__ float seg_cum(float t, float mn, float mx) {
    return fminf(fmaxf(t, mn), mx) - mn;
}

// First difference of the per-bin overlap U(i) of [mn,mx] with bin i.
// Exactly 0 for i outside {i0, i0+1, i1, i1+1}.
__device__ __forceinline__ float second_diff(int i, float bs, float mn, float mx) {
    float u2 = seg_cum((float)(i + 1) * bs, mn, mx);
    float u1 = seg_cum((float)(i) * bs, mn, mx);
    float u0 = seg_cum((float)(i - 1) * bs, mn, mx);
    return (u2 - u1) - (u1 - u0);
}

// Pass 1: 8 lanes per net; shfl butterfly min/max; lane 0 writes bbox.
// Invalid/padded nets get a sentinel (xmx < xmn) so later passes skip them.
__global__ void __launch_bounds__(256) net_bbox(
    const float* __restrict__ pin_pos,
    const int* __restrict__ netpin_start,
    const int* __restrict__ flat_netpin,
    float4* __restrict__ bbox4,
    int num_nets, int Np) {
    int n = blockIdx.x * 32 + (threadIdx.x >> 3);
    int l = threadIdx.x & 7;
    if (n >= Np) return;
    int s = 0, e = 0;
    if (n < num_nets) {
        s = netpin_start[n];
        e = netpin_start[n + 1];
    }
    float xmn = 3.0e38f, xmx = -3.0e38f, ymn = 3.0e38f, ymx = -3.0e38f;
    for (int p = s + l; p < e; p += 8) {
        int ip = flat_netpin[p];
        float2 xy = *reinterpret_cast<const float2*>(pin_pos + 2 * (size_t)ip);
        xmn = fminf(xmn, xy.x);
        xmx = fmaxf(xmx, xy.x);
        ymn = fminf(ymn, xy.y);
        ymx = fmaxf(ymx, xy.y);
    }
#pragma unroll
    for (int m = 1; m < 8; m <<= 1) {
        xmn = fminf(xmn, __shfl_xor(xmn, m));
        xmx = fmaxf(xmx, __shfl_xor(xmx, m));
        ymn = fminf(ymn, __shfl_xor(ymn, m));
        ymx = fmaxf(ymx, __shfl_xor(ymx, m));
    }
    if (l == 0) {
        bbox4[n] = (e <= s) ? make_float4(3.0e38f, -3.0e38f, 3.0e38f, -3.0e38f)
                            : make_float4(xmn, xmx, ymn, ymx);
    }
}

// Pass 2: bin nets into row-pair buckets. Per block: LDS histogram of the
// 128 pair counters, one global atomicAdd per (block,pair) to reserve a
// range, then each thread writes its net id at base+localrank.
__global__ void __launch_bounds__(256) bucket_scatter(
    const float4* __restrict__ bbox4,
    unsigned* __restrict__ gcount,
    int* __restrict__ bucket,
    int cap, int Np) {
    __shared__ unsigned cnt[NPAIR];
    __shared__ unsigned base[NPAIR];
    __shared__ unsigned loc[NPAIR];
    int tid = threadIdx.x;
    int n = blockIdx.x * 256 + tid;
    if (tid < NPAIR) { cnt[tid] = 0; loc[tid] = 0; }
    __syncthreads();

    int pl[4];
    int npr = 0;
    if (n < Np) {
        float4 bb = bbox4[n];
        if (bb.y >= bb.x) {                       // valid net
            int i0 = (int)floorf(bb.x * 0.5f);
            int i1 = (int)floorf(bb.y * 0.5f);
            int a = i0 >> 1, b = (i0 + 1) >> 1;
            int c = i1 >> 1, d = (i1 + 1) >> 1;   // pairs of the 4 target rows
            pl[npr++] = a;                        // a <= 127 always
            if (b != a && b < NPAIR) pl[npr++] = b;
            if (c != a && c != b) pl[npr++] = c;  // c <= 127 always
            if (d != a && d != b && d != c && d < NPAIR) pl[npr++] = d;
        }
    }
    for (int k = 0; k < npr; ++k) atomicAdd(&cnt[pl[k]], 1u);
    __syncthreads();
    if (tid < NPAIR && cnt[tid] > 0)
        base[tid] = atomicAdd(&gcount[tid], cnt[tid]);
    __syncthreads();
    for (int k = 0; k < npr; ++k) {
        int p = pl[k];
        unsigned slot = base[p] + atomicAdd(&loc[p], 1u);
        if (slot < (unsigned)cap) bucket[p * cap + slot] = n;
    }
}

// Pass 3: block (slice, pair) processes its bucket chunk densely; deposits
// into 4 KB of LDS row accumulators (rows 2p, 2p+1); writes partial rows.
__global__ void __launch_bounds__(256) row_build_bucketed(
    const float4* __restrict__ bbox4,
    const float* __restrict__ net_weights,
    const unsigned* __restrict__ gcount,
    const int* __restrict__ bucket,
    int cap,
    float2* __restrict__ Dpart) {
    __shared__ float h0[NBY], v0[NBY], h1[NBY], v1[NBY];
    const int pair  = blockIdx.x & (NPAIR - 1);
    const int slice = blockIdx.x >> 7;
    const int tid   = threadIdx.x;
    h0[tid] = 0.f; v0[tid] = 0.f; h1[tid] = 0.f; v1[tid] = 0.f;
    __syncthreads();

    const int r0 = pair * 2, r1 = r0 + 1;
    int cnt = min((int)gcount[pair], cap);
    int chunk = (cnt + SLICES - 1) / SLICES;
    int qb = slice * chunk;
    int qe = min(qb + chunk, cnt);

    for (int q = qb + tid; q < qe; q += 256) {
        int n = bucket[pair * cap + q];
        float4 bb = bbox4[n];
        float w = net_weights[n];
        float wh = w / (bb.w - bb.z);
        float wv = w / (bb.y - bb.x);
        float dA = second_diff(r0, BSX, bb.x, bb.y);
        float dB = second_diff(r1, BSX, bb.x, bb.y);
        int j0 = (int)floorf(bb.z * 0.5f);
        int j1 = (int)floorf(bb.w * 0.5f);
        int yi[4];
        yi[0] = j0;
        yi[1] = j0 + 1;
        yi[2] = (j1 > j0 + 1) ? j1 : -1;          // dedup overlapping cands
        yi[3] = (j1 > j0) ? j1 + 1 : -1;
#pragma unroll
        for (int c2 = 0; c2 < 4; ++c2) {
            int y = yi[c2];
            if (y >= 0 && y < NBY) {
                float dy = second_diff(y, BSY, bb.z, bb.w);
                if (dy != 0.0f) {
                    if (dA != 0.0f) {
                        atomicAdd(&h0[y], wh * dA * dy);
                        atomicAdd(&v0[y], wv * dA * dy);
                    }
                    if (dB != 0.0f) {
                        atomicAdd(&h1[y], wh * dB * dy);
                        atomicAdd(&v1[y], wv * dB * dy);
                    }
                }
            }
        }
    }
    __syncthreads();
    size_t b = (size_t)slice * NMAP;
    Dpart[b + (size_t)r0 * NBY + tid] = make_float2(h0[tid], v0[tid]);
    Dpart[b + (size_t)r1 * NBY + tid] = make_float2(h1[tid], v1[tid]);
}

// Pass 4: fold slices + inclusive y-scan; result -> slice 0.
__global__ void __launch_bounds__(256) scan_rows_fold(float2* __restrict__ Dpart, int S) {
    __shared__ float bh[NBY];
    __shared__ float bv[NBY];
    int r = blockIdx.x;
    int y = threadIdx.x;
    float h = 0.0f, v = 0.0f;
    for (int s = 0; s < S; ++s) {
        float2 t = Dpart[(size_t)s * NMAP + r * NBY + y];
        h += t.x;
        v += t.y;
    }
    bh[y] = h;
    bv[y] = v;
    __syncthreads();
    for (int off = 1; off < NBY; off <<= 1) {
        float ah = (y >= off) ? bh[y - off] : 0.0f;
        float av = (y >= off) ? bv[y - off] : 0.0f;
        __syncthreads();
        bh[y] += ah;
        bv[y] += av;
        __syncthreads();
    }
    Dpart[r * NBY + y] = make_float2(bh[y], bv[y]);   // writes own read slot
}

// Pass 5: inclusive scan along x per column (one block per y) + finalize.
__global__ void __launch_bounds__(256) scan_cols_finalize(
    const float2* __restrict__ D,
    const float* __restrict__ init_h,
    const float* __restrict__ init_v,
    float* __restrict__ out) {
    __shared__ float bh[NBX];
    __shared__ float bv[NBX];
    int y = blockIdx.x;
    int x = threadIdx.x;
    float2 t = D[x * NBY + y];
    bh[x] = t.x;
    bv[x] = t.y;
    __syncthreads();
    for (int off = 1; off < NBX; off <<= 1) {
        float ah = (x >= off) ? bh[x - off] : 0.0f;
        float av = (x >= off) ? bv[x - off] : 0.0f;
        __syncthreads();
        bh[x] += ah;
        bv[x] += av;
        __syncthreads();
    }
    int idx = x * NBY + y;
    float H = fmaf(bh[x], INV_H, init_h[idx]);
    float V = fmaf(bv[x], INV_V, init_v[idx]);
    float r = fmaxf(fabsf(H), fabsf(V));
    out[idx]            = r;
    out[idx + NMAP]     = H;
    out[idx + 2 * NMAP] = V;
}

extern "C" void kernel_launch(void* const* d_in, const int* in_sizes, int n_in,
                              void* d_out, int out_size, void* d_ws, size_t ws_size,
                              hipStream_t stream) {
    const float* pin_pos      = (const float*)d_in[0];
    const int*   netpin_start = (const int*)d_in[1];
    const int*   flat_netpin  = (const int*)d_in[2];
    const float* net_weights  = (const float*)d_in[3];
    const float* init_h       = (const float*)d_in[4];
    const float* init_v       = (const float*)d_in[5];
    float* out = (float*)d_out;

    int num_nets = in_sizes[3];                       // net_weights length
    int Np = (num_nets + 255) & ~255;                 // padded net count

    // ws layout: [bbox4: Np*16][gcount: 512][bucket: 128*cap*4][Dpart: S*NMAP*8]
    char* w = (char*)d_ws;
    float4*   bbox4  = (float4*)w;
    unsigned* gcount = (unsigned*)(w + (size_t)Np * 16);
    int*      bucket = (int*)(w + (size_t)Np * 16 + 512);

    size_t fixed = (size_t)Np * 16 + 512 + (size_t)SLICES * NMAP * sizeof(float2);
    long long avail = (long long)ws_size - (long long)fixed;
    int cap = (int)(avail / (NPAIR * 4));
    if (cap > CAPMAX) cap = CAPMAX;
    if (cap < 4) cap = 4;
    cap &= ~3;                                        // keep Dpart 16B-aligned
    float2* Dpart = (float2*)(w + (size_t)Np * 16 + 512 + (size_t)NPAIR * cap * 4);

    hipMemsetAsync(gcount, 0, NPAIR * sizeof(unsigned), stream);

    net_bbox<<<Np / 32, 256, 0, stream>>>(pin_pos, netpin_start, flat_netpin,
                                          bbox4, num_nets, Np);
    bucket_scatter<<<Np / 256, 256, 0, stream>>>(bbox4, gcount, bucket, cap, Np);
    row_build_bucketed<<<NPAIR * SLICES, 256, 0, stream>>>(
        bbox4, net_weights, gcount, bucket, cap, Dpart);
    scan_rows_fold<<<NBX, 256, 0, stream>>>(Dpart, SLICES);
    scan_cols_finalize<<<NBY, 256, 0, stream>>>(Dpart, init_h, init_v, out);
}

// Round 9
// 96.160 us; speedup vs baseline: 1.9396x; 1.0207x over previous
//
#include <hip/hip_runtime.h>
#include <hip/hip_bf16.h>

// RUDY routing-demand maps via difference-domain + 2D prefix sum.
// Each net deposits wt * u(x) ⊗ v(y); du has <=4 nonzeros (rows i0,i0+1,
// i1,i1+1) -> <=16 difference cells/net; one scan per dim reconstructs maps.
//
// Round-9: r8's row_build (60 us) was straggler-bound (occupancy 3.4%,
// VALU 2% but VALU-work arithmetic closes) from skewed buckets (edge pairs
// ~9k entries vs mean 2.3k) + silent cap-8192 overflow (absmax 0.031->0.047).
// Fix: exact-offset buckets (count -> prefix -> place, no drops) +
// count-proportional chunk plan (<=1024 items/block, <=544 blocks, built
// on-device). Plus two diagnostic twins (NOATOMIC / NOLOAD) to attribute
// any residual per-iteration cost next round.

#define NBX 256
#define NBY 256
#define NMAP (NBX * NBY)
#define NPAIR 128
#define ITEMS 1024u        // target items per chunk
#define MAXCH 544          // >= NPAIR + 4*Np/ITEMS worst case

constexpr float BSX = 2.0f;
constexpr float BSY = 2.0f;
constexpr float INV_H = 1.0f / (4.0f * 50.0f);
constexpr float INV_V = 1.0f / (4.0f * 40.0f);

__device__ __forceinline__ float seg_cum(float t, float mn, float mx) {
    return fminf(fmaxf(t, mn), mx) - mn;
}
// First difference of per-bin overlap of [mn,mx]; nonzero only at
// {i0, i0+1, i1, i1+1}.
__device__ __forceinline__ float second_diff(int i, float bs, float mn, float mx) {
    float u2 = seg_cum((float)(i + 1) * bs, mn, mx);
    float u1 = seg_cum((float)(i) * bs, mn, mx);
    float u0 = seg_cum((float)(i - 1) * bs, mn, mx);
    return (u2 - u1) - (u1 - u0);
}
// Row-pair buckets this net touches (deduped, <=4).
__device__ __forceinline__ int net_pairs(float4 bb, int* pl) {
    if (bb.y < bb.x) return 0;                 // sentinel / padding
    int i0 = (int)floorf(bb.x * 0.5f);
    int i1 = (int)floorf(bb.y * 0.5f);
    int a = i0 >> 1, b = (i0 + 1) >> 1, c = i1 >> 1, d = (i1 + 1) >> 1;
    int n = 0;
    pl[n++] = a;
    if (b != a && b < NPAIR) pl[n++] = b;
    if (c != a && c != b) pl[n++] = c;
    if (d != a && d != b && d != c && d < NPAIR) pl[n++] = d;
    return n;
}

// Pass 1: 8 lanes/net, shfl butterfly bbox reduce.
__global__ void __launch_bounds__(256) net_bbox(
    const float* __restrict__ pin_pos,
    const int* __restrict__ netpin_start,
    const int* __restrict__ flat_netpin,
    float4* __restrict__ bbox4,
    int num_nets, int Np) {
    int n = blockIdx.x * 32 + (threadIdx.x >> 3);
    int l = threadIdx.x & 7;
    if (n >= Np) return;
    int s = 0, e = 0;
    if (n < num_nets) {
        s = netpin_start[n];
        e = netpin_start[n + 1];
    }
    float xmn = 3.0e38f, xmx = -3.0e38f, ymn = 3.0e38f, ymx = -3.0e38f;
    for (int p = s + l; p < e; p += 8) {
        int ip = flat_netpin[p];
        float2 xy = *reinterpret_cast<const float2*>(pin_pos + 2 * (size_t)ip);
        xmn = fminf(xmn, xy.x);
        xmx = fmaxf(xmx, xy.x);
        ymn = fminf(ymn, xy.y);
        ymx = fmaxf(ymx, xy.y);
    }
#pragma unroll
    for (int m = 1; m < 8; m <<= 1) {
        xmn = fminf(xmn, __shfl_xor(xmn, m));
        xmx = fmaxf(xmx, __shfl_xor(xmx, m));
        ymn = fminf(ymn, __shfl_xor(ymn, m));
        ymx = fmaxf(ymx, __shfl_xor(ymx, m));
    }
    if (l == 0) {
        bbox4[n] = (e <= s) ? make_float4(3.0e38f, -3.0e38f, 3.0e38f, -3.0e38f)
                            : make_float4(xmn, xmx, ymn, ymx);
    }
}

// Pass 2a: per-pair global counts (LDS-aggregated).
__global__ void __launch_bounds__(256) bucket_count(
    const float4* __restrict__ bbox4, unsigned* __restrict__ gcount, int Np) {
    __shared__ unsigned cnt[NPAIR];
    int tid = threadIdx.x, n = blockIdx.x * 256 + tid;
    if (tid < NPAIR) cnt[tid] = 0;
    __syncthreads();
    int pl[4];
    int k = (n < Np) ? net_pairs(bbox4[n], pl) : 0;
    for (int i = 0; i < k; ++i) atomicAdd(&cnt[pl[i]], 1u);
    __syncthreads();
    if (tid < NPAIR && cnt[tid]) atomicAdd(&gcount[tid], cnt[tid]);
}

// Pass 2b: plan — prefix offsets + count-proportional chunk descriptors.
__global__ void __launch_bounds__(128) plan_build(
    const unsigned* __restrict__ gcount, unsigned* __restrict__ gcursor,
    int4* __restrict__ chunks, int* __restrict__ cbeg, int* __restrict__ ckc,
    int* __restrict__ hdr) {
    __shared__ unsigned soff[NPAIR];
    __shared__ unsigned scb[NPAIR];
    int p = threadIdx.x;
    unsigned cnt = gcount[p];
    int kc = 1 + (int)(cnt / ITEMS);
    soff[p] = cnt;
    scb[p] = (unsigned)kc;
    __syncthreads();
    for (int off = 1; off < NPAIR; off <<= 1) {
        unsigned a = (p >= off) ? soff[p - off] : 0u;
        unsigned b = (p >= off) ? scb[p - off] : 0u;
        __syncthreads();
        soff[p] += a;
        scb[p] += b;
        __syncthreads();
    }
    unsigned obeg = soff[p] - cnt;          // exclusive bucket offset
    unsigned cb   = scb[p] - (unsigned)kc;  // exclusive chunk offset
    gcursor[p] = obeg;
    cbeg[p] = (int)cb;
    ckc[p] = kc;
    unsigned span = (cnt + (unsigned)kc - 1) / (unsigned)kc;
    for (int j = 0; j < kc; ++j) {
        unsigned b = obeg + (unsigned)j * span;
        unsigned e2 = min(b + span, obeg + cnt);
        if (b > e2) b = e2;
        chunks[cb + j] = make_int4(p, (int)b, (int)e2, 0);
    }
    if (p == NPAIR - 1) hdr[0] = (int)scb[p];
}

// Pass 2c: place net ids at exact offsets (no cap, no drops).
__global__ void __launch_bounds__(256) bucket_place(
    const float4* __restrict__ bbox4, unsigned* __restrict__ gcursor,
    int* __restrict__ bucket, int Np) {
    __shared__ unsigned cnt[NPAIR], base[NPAIR], loc[NPAIR];
    int tid = threadIdx.x, n = blockIdx.x * 256 + tid;
    if (tid < NPAIR) { cnt[tid] = 0; loc[tid] = 0; }
    __syncthreads();
    int pl[4];
    int k = (n < Np) ? net_pairs(bbox4[n], pl) : 0;
    for (int i = 0; i < k; ++i) atomicAdd(&cnt[pl[i]], 1u);
    __syncthreads();
    if (tid < NPAIR && cnt[tid]) base[tid] = atomicAdd(&gcursor[tid], cnt[tid]);
    __syncthreads();
    for (int i = 0; i < k; ++i) {
        int p = pl[i];
        bucket[base[p] + atomicAdd(&loc[p], 1u)] = n;
    }
}

// Pass 3: one block per chunk (balanced). MODE 0 = real; 1 = NOATOMIC twin
// (asm sink, no LDS atomics); 2 = NOLOAD twin (synthesized bbox/weight).
template <int MODE>
__global__ void __launch_bounds__(256) chunk_build(
    const float4* __restrict__ bbox4,
    const float* __restrict__ net_weights,
    const int* __restrict__ bucket,
    const int4* __restrict__ chunks,
    const int* __restrict__ hdr,
    float2* __restrict__ Dsub) {
    int bid = blockIdx.x;
    if (bid >= hdr[0]) return;
    int4 ch = chunks[bid];
    const int pair = ch.x, beg = ch.y, end = ch.z;
    __shared__ float h0[NBY], v0[NBY], h1[NBY], v1[NBY];
    int tid = threadIdx.x;
    h0[tid] = 0.f; v0[tid] = 0.f; h1[tid] = 0.f; v1[tid] = 0.f;
    __syncthreads();
    const int r0 = pair * 2, r1 = r0 + 1;

    for (int q = beg + tid; q < end; q += 256) {
        int id = bucket[q];
        float4 bb;
        float w;
        if (MODE == 2) {            // no random gathers: synthesize payload
            float fx = (float)(id & 1023) * 0.25f;
            bb = make_float4(fx, fx + 7.0f, fx * 0.37f, fx * 0.37f + 9.0f);
            w = 1.0f;
        } else {
            bb = bbox4[id];
            w = net_weights[id];
        }
        float wh = w / (bb.w - bb.z);
        float wv = w / (bb.y - bb.x);
        float dA = second_diff(r0, BSX, bb.x, bb.y);
        float dB = second_diff(r1, BSX, bb.x, bb.y);
        int j0 = (int)floorf(bb.z * 0.5f);
        int j1 = (int)floorf(bb.w * 0.5f);
        int yi[4];
        yi[0] = j0;
        yi[1] = j0 + 1;
        yi[2] = (j1 > j0 + 1) ? j1 : -1;
        yi[3] = (j1 > j0) ? j1 + 1 : -1;
#pragma unroll
        for (int c2 = 0; c2 < 4; ++c2) {
            int y = yi[c2];
            if (y >= 0 && y < NBY) {
                float dy = second_diff(y, BSY, bb.z, bb.w);
                if (dy != 0.0f) {
                    float a0 = wh * dA * dy, b0 = wv * dA * dy;
                    float a1 = wh * dB * dy, b1 = wv * dB * dy;
                    if (MODE == 1) {
                        asm volatile("" :: "v"(a0), "v"(b0), "v"(a1), "v"(b1));
                    } else {
                        if (dA != 0.0f) {
                            atomicAdd(&h0[y], a0);
                            atomicAdd(&v0[y], b0);
                        }
                        if (dB != 0.0f) {
                            atomicAdd(&h1[y], a1);
                            atomicAdd(&v1[y], b1);
                        }
                    }
                }
            }
        }
    }
    __syncthreads();
    size_t b = (size_t)bid * 2 * NBY;
    Dsub[b + tid]       = make_float2(h0[tid], v0[tid]);
    Dsub[b + NBY + tid] = make_float2(h1[tid], v1[tid]);
}

// Pass 4: per row, fold that pair's chunks + inclusive y-scan -> D.
__global__ void __launch_bounds__(256) fold_rows(
    const float2* __restrict__ Dsub,
    const int* __restrict__ cbeg, const int* __restrict__ ckc,
    float2* __restrict__ D) {
    __shared__ float bh[NBY];
    __shared__ float bv[NBY];
    int r = blockIdx.x, y = threadIdx.x;
    int p = r >> 1, par = r & 1;
    int cb = cbeg[p], kc = ckc[p];
    float h = 0.f, v = 0.f;
    for (int j = 0; j < kc; ++j) {
        float2 t = Dsub[((size_t)(cb + j) * 2 + par) * NBY + y];
        h += t.x;
        v += t.y;
    }
    bh[y] = h;
    bv[y] = v;
    __syncthreads();
    for (int off = 1; off < NBY; off <<= 1) {
        float ah = (y >= off) ? bh[y - off] : 0.0f;
        float av = (y >= off) ? bv[y - off] : 0.0f;
        __syncthreads();
        bh[y] += ah;
        bv[y] += av;
        __syncthreads();
    }
    D[r * NBY + y] = make_float2(bh[y], bv[y]);
}

// Pass 5: inclusive x-scan per column + finalize.
__global__ void __launch_bounds__(256) scan_cols_finalize(
    const float2* __restrict__ D,
    const float* __restrict__ init_h,
    const float* __restrict__ init_v,
    float* __restrict__ out) {
    __shared__ float bh[NBX];
    __shared__ float bv[NBX];
    int y = blockIdx.x;
    int x = threadIdx.x;
    float2 t = D[x * NBY + y];
    bh[x] = t.x;
    bv[x] = t.y;
    __syncthreads();
    for (int off = 1; off < NBX; off <<= 1) {
        float ah = (x >= off) ? bh[x - off] : 0.0f;
        float av = (x >= off) ? bv[x - off] : 0.0f;
        __syncthreads();
        bh[x] += ah;
        bv[x] += av;
        __syncthreads();
    }
    int idx = x * NBY + y;
    float H = fmaf(bh[x], INV_H, init_h[idx]);
    float V = fmaf(bv[x], INV_V, init_v[idx]);
    float r = fmaxf(fabsf(H), fabsf(V));
    out[idx]            = r;
    out[idx + NMAP]     = H;
    out[idx + 2 * NMAP] = V;
}

extern "C" void kernel_launch(void* const* d_in, const int* in_sizes, int n_in,
                              void* d_out, int out_size, void* d_ws, size_t ws_size,
                              hipStream_t stream) {
    const float* pin_pos      = (const float*)d_in[0];
    const int*   netpin_start = (const int*)d_in[1];
    const int*   flat_netpin  = (const int*)d_in[2];
    const float* net_weights  = (const float*)d_in[3];
    const float* init_h       = (const float*)d_in[4];
    const float* init_v       = (const float*)d_in[5];
    float* out = (float*)d_out;

    int num_nets = in_sizes[3];
    int Np = (num_nets + 255) & ~255;

    // ws layout (~5.9 MB @100k nets):
    // [bbox4 Np*16][Dsub MAXCH*2*256*8][D NMAP*8][bucket 4*Np*4]
    // [chunks MAXCH*16][cbeg 512][ckc 512][gcount 512][gcursor 512][hdr 64]
    char* w = (char*)d_ws;
    size_t o = 0;
    float4*   bbox4   = (float4*)(w + o);   o += (size_t)Np * 16;
    float2*   Dsub    = (float2*)(w + o);   o += (size_t)MAXCH * 2 * NBY * 8;
    float2*   D       = (float2*)(w + o);   o += (size_t)NMAP * 8;
    int*      bucket  = (int*)(w + o);      o += (size_t)4 * Np * 4;
    int4*     chunks  = (int4*)(w + o);     o += (size_t)MAXCH * 16;
    int*      cbeg    = (int*)(w + o);      o += 512;
    int*      ckc     = (int*)(w + o);      o += 512;
    unsigned* gcount  = (unsigned*)(w + o); o += 512;
    unsigned* gcursor = (unsigned*)(w + o); o += 512;
    int*      hdr     = (int*)(w + o);      o += 64;

    hipMemsetAsync(gcount, 0, NPAIR * sizeof(unsigned), stream);

    net_bbox<<<Np / 32, 256, 0, stream>>>(pin_pos, netpin_start, flat_netpin,
                                          bbox4, num_nets, Np);
    bucket_count<<<Np / 256, 256, 0, stream>>>(bbox4, gcount, Np);
    plan_build<<<1, 128, 0, stream>>>(gcount, gcursor, chunks, cbeg, ckc, hdr);
    bucket_place<<<Np / 256, 256, 0, stream>>>(bbox4, gcursor, bucket, Np);
    // Diagnostic twins first (their Dsub writes are overwritten by the real
    // pass); remove once the mechanism is attributed.
    chunk_build<1><<<MAXCH, 256, 0, stream>>>(bbox4, net_weights, bucket,
                                              chunks, hdr, Dsub);
    chunk_build<2><<<MAXCH, 256, 0, stream>>>(bbox4, net_weights, bucket,
                                              chunks, hdr, Dsub);
    chunk_build<0><<<MAXCH, 256, 0, stream>>>(bbox4, net_weights, bucket,
                                              chunks, hdr, Dsub);
    fold_rows<<<NBX, 256, 0, stream>>>(Dsub, cbeg, ckc, D);
    scan_cols_finalize<<<NBY, 256, 0, stream>>>(D, init_h, init_v, out);
}

// Round 10
// 79.500 us; speedup vs baseline: 2.3461x; 1.2096x over previous
//
#include <hip/hip_runtime.h>
#include <hip/hip_bf16.h>

// RUDY routing-demand maps via difference-domain + 2D prefix sum.
// Each net deposits wt * u(x) ⊗ v(y); du has <=4 nonzeros (rows i0,i0+1,
// i1,i1+1) -> <=16 difference cells/net; one scan per dim reconstructs maps.
//
// Round-10: round-9 profile showed hipMemsetAsync(512 B) costs ~40 us/replay
// as __amd_rocclr_fillBufferAligned (8 KB traffic, all pipes idle) — the
// dominant dispatch. Fix: zero gcount from net_bbox block 0 (stream order
// guarantees it lands before bucket_count). Diagnostic twins removed (the
// profile attributed the r8 mystery cost to the fill, not gather/atomics).
// Pipeline: bbox -> count -> plan (balanced chunks) -> place -> build ->
// fold+y-scan -> x-scan+finalize. Zero per-cell global atomics.

#define NBX 256
#define NBY 256
#define NMAP (NBX * NBY)
#define NPAIR 128
#define ITEMS 1024u        // target items per chunk
#define MAXCH 544          // >= NPAIR + 4*Np/ITEMS worst case

constexpr float BSX = 2.0f;
constexpr float BSY = 2.0f;
constexpr float INV_H = 1.0f / (4.0f * 50.0f);
constexpr float INV_V = 1.0f / (4.0f * 40.0f);

__device__ __forceinline__ float seg_cum(float t, float mn, float mx) {
    return fminf(fmaxf(t, mn), mx) - mn;
}
// First difference of per-bin overlap of [mn,mx]; nonzero only at
// {i0, i0+1, i1, i1+1}.
__device__ __forceinline__ float second_diff(int i, float bs, float mn, float mx) {
    float u2 = seg_cum((float)(i + 1) * bs, mn, mx);
    float u1 = seg_cum((float)(i) * bs, mn, mx);
    float u0 = seg_cum((float)(i - 1) * bs, mn, mx);
    return (u2 - u1) - (u1 - u0);
}
// Row-pair buckets this net touches (deduped, <=4).
__device__ __forceinline__ int net_pairs(float4 bb, int* pl) {
    if (bb.y < bb.x) return 0;                 // sentinel / padding
    int i0 = (int)floorf(bb.x * 0.5f);
    int i1 = (int)floorf(bb.y * 0.5f);
    int a = i0 >> 1, b = (i0 + 1) >> 1, c = i1 >> 1, d = (i1 + 1) >> 1;
    int n = 0;
    pl[n++] = a;
    if (b != a && b < NPAIR) pl[n++] = b;
    if (c != a && c != b) pl[n++] = c;
    if (d != a && d != b && d != c && d < NPAIR) pl[n++] = d;
    return n;
}

// Pass 1: 8 lanes/net, shfl butterfly bbox reduce. Block 0 also zeroes
// gcount (replaces the 40-us fillBufferAligned; stream order protects it).
__global__ void __launch_bounds__(256) net_bbox(
    const float* __restrict__ pin_pos,
    const int* __restrict__ netpin_start,
    const int* __restrict__ flat_netpin,
    float4* __restrict__ bbox4,
    unsigned* __restrict__ gcount,
    int num_nets, int Np) {
    if (blockIdx.x == 0 && threadIdx.x < NPAIR) gcount[threadIdx.x] = 0u;
    int n = blockIdx.x * 32 + (threadIdx.x >> 3);
    int l = threadIdx.x & 7;
    if (n >= Np) return;
    int s = 0, e = 0;
    if (n < num_nets) {
        s = netpin_start[n];
        e = netpin_start[n + 1];
    }
    float xmn = 3.0e38f, xmx = -3.0e38f, ymn = 3.0e38f, ymx = -3.0e38f;
    for (int p = s + l; p < e; p += 8) {
        int ip = flat_netpin[p];
        float2 xy = *reinterpret_cast<const float2*>(pin_pos + 2 * (size_t)ip);
        xmn = fminf(xmn, xy.x);
        xmx = fmaxf(xmx, xy.x);
        ymn = fminf(ymn, xy.y);
        ymx = fmaxf(ymx, xy.y);
    }
#pragma unroll
    for (int m = 1; m < 8; m <<= 1) {
        xmn = fminf(xmn, __shfl_xor(xmn, m));
        xmx = fmaxf(xmx, __shfl_xor(xmx, m));
        ymn = fminf(ymn, __shfl_xor(ymn, m));
        ymx = fmaxf(ymx, __shfl_xor(ymx, m));
    }
    if (l == 0) {
        bbox4[n] = (e <= s) ? make_float4(3.0e38f, -3.0e38f, 3.0e38f, -3.0e38f)
                            : make_float4(xmn, xmx, ymn, ymx);
    }
}

// Pass 2a: per-pair global counts (LDS-aggregated).
__global__ void __launch_bounds__(256) bucket_count(
    const float4* __restrict__ bbox4, unsigned* __restrict__ gcount, int Np) {
    __shared__ unsigned cnt[NPAIR];
    int tid = threadIdx.x, n = blockIdx.x * 256 + tid;
    if (tid < NPAIR) cnt[tid] = 0;
    __syncthreads();
    int pl[4];
    int k = (n < Np) ? net_pairs(bbox4[n], pl) : 0;
    for (int i = 0; i < k; ++i) atomicAdd(&cnt[pl[i]], 1u);
    __syncthreads();
    if (tid < NPAIR && cnt[tid]) atomicAdd(&gcount[tid], cnt[tid]);
}

// Pass 2b: plan — prefix offsets + count-proportional chunk descriptors.
__global__ void __launch_bounds__(128) plan_build(
    const unsigned* __restrict__ gcount, unsigned* __restrict__ gcursor,
    int4* __restrict__ chunks, int* __restrict__ cbeg, int* __restrict__ ckc,
    int* __restrict__ hdr) {
    __shared__ unsigned soff[NPAIR];
    __shared__ unsigned scb[NPAIR];
    int p = threadIdx.x;
    unsigned cnt = gcount[p];
    int kc = 1 + (int)(cnt / ITEMS);
    soff[p] = cnt;
    scb[p] = (unsigned)kc;
    __syncthreads();
    for (int off = 1; off < NPAIR; off <<= 1) {
        unsigned a = (p >= off) ? soff[p - off] : 0u;
        unsigned b = (p >= off) ? scb[p - off] : 0u;
        __syncthreads();
        soff[p] += a;
        scb[p] += b;
        __syncthreads();
    }
    unsigned obeg = soff[p] - cnt;          // exclusive bucket offset
    unsigned cb   = scb[p] - (unsigned)kc;  // exclusive chunk offset
    gcursor[p] = obeg;
    cbeg[p] = (int)cb;
    ckc[p] = kc;
    unsigned span = (cnt + (unsigned)kc - 1) / (unsigned)kc;
    for (int j = 0; j < kc; ++j) {
        unsigned b = obeg + (unsigned)j * span;
        unsigned e2 = min(b + span, obeg + cnt);
        if (b > e2) b = e2;
        chunks[cb + j] = make_int4(p, (int)b, (int)e2, 0);
    }
    if (p == NPAIR - 1) hdr[0] = (int)scb[p];
}

// Pass 2c: place net ids at exact offsets (no cap, no drops).
__global__ void __launch_bounds__(256) bucket_place(
    const float4* __restrict__ bbox4, unsigned* __restrict__ gcursor,
    int* __restrict__ bucket, int Np) {
    __shared__ unsigned cnt[NPAIR], base[NPAIR], loc[NPAIR];
    int tid = threadIdx.x, n = blockIdx.x * 256 + tid;
    if (tid < NPAIR) { cnt[tid] = 0; loc[tid] = 0; }
    __syncthreads();
    int pl[4];
    int k = (n < Np) ? net_pairs(bbox4[n], pl) : 0;
    for (int i = 0; i < k; ++i) atomicAdd(&cnt[pl[i]], 1u);
    __syncthreads();
    if (tid < NPAIR && cnt[tid]) base[tid] = atomicAdd(&gcursor[tid], cnt[tid]);
    __syncthreads();
    for (int i = 0; i < k; ++i) {
        int p = pl[i];
        bucket[base[p] + atomicAdd(&loc[p], 1u)] = n;
    }
}

// Pass 3: one block per chunk (balanced, <=1024 items).
__global__ void __launch_bounds__(256) chunk_build(
    const float4* __restrict__ bbox4,
    const float* __restrict__ net_weights,
    const int* __restrict__ bucket,
    const int4* __restrict__ chunks,
    const int* __restrict__ hdr,
    float2* __restrict__ Dsub) {
    int bid = blockIdx.x;
    if (bid >= hdr[0]) return;
    int4 ch = chunks[bid];
    const int pair = ch.x, beg = ch.y, end = ch.z;
    __shared__ float h0[NBY], v0[NBY], h1[NBY], v1[NBY];
    int tid = threadIdx.x;
    h0[tid] = 0.f; v0[tid] = 0.f; h1[tid] = 0.f; v1[tid] = 0.f;
    __syncthreads();
    const int r0 = pair * 2, r1 = r0 + 1;

    for (int q = beg + tid; q < end; q += 256) {
        int id = bucket[q];
        float4 bb = bbox4[id];
        float w = net_weights[id];
        float wh = w / (bb.w - bb.z);
        float wv = w / (bb.y - bb.x);
        float dA = second_diff(r0, BSX, bb.x, bb.y);
        float dB = second_diff(r1, BSX, bb.x, bb.y);
        int j0 = (int)floorf(bb.z * 0.5f);
        int j1 = (int)floorf(bb.w * 0.5f);
        int yi[4];
        yi[0] = j0;
        yi[1] = j0 + 1;
        yi[2] = (j1 > j0 + 1) ? j1 : -1;
        yi[3] = (j1 > j0) ? j1 + 1 : -1;
#pragma unroll
        for (int c2 = 0; c2 < 4; ++c2) {
            int y = yi[c2];
            if (y >= 0 && y < NBY) {
                float dy = second_diff(y, BSY, bb.z, bb.w);
                if (dy != 0.0f) {
                    if (dA != 0.0f) {
                        atomicAdd(&h0[y], wh * dA * dy);
                        atomicAdd(&v0[y], wv * dA * dy);
                    }
                    if (dB != 0.0f) {
                        atomicAdd(&h1[y], wh * dB * dy);
                        atomicAdd(&v1[y], wv * dB * dy);
                    }
                }
            }
        }
    }
    __syncthreads();
    size_t b = (size_t)bid * 2 * NBY;
    Dsub[b + tid]       = make_float2(h0[tid], v0[tid]);
    Dsub[b + NBY + tid] = make_float2(h1[tid], v1[tid]);
}

// Pass 4: per row, fold that pair's chunks + inclusive y-scan -> D.
__global__ void __launch_bounds__(256) fold_rows(
    const float2* __restrict__ Dsub,
    const int* __restrict__ cbeg, const int* __restrict__ ckc,
    float2* __restrict__ D) {
    __shared__ float bh[NBY];
    __shared__ float bv[NBY];
    int r = blockIdx.x, y = threadIdx.x;
    int p = r >> 1, par = r & 1;
    int cb = cbeg[p], kc = ckc[p];
    float h = 0.f, v = 0.f;
    for (int j = 0; j < kc; ++j) {
        float2 t = Dsub[((size_t)(cb + j) * 2 + par) * NBY + y];
        h += t.x;
        v += t.y;
    }
    bh[y] = h;
    bv[y] = v;
    __syncthreads();
    for (int off = 1; off < NBY; off <<= 1) {
        float ah = (y >= off) ? bh[y - off] : 0.0f;
        float av = (y >= off) ? bv[y - off] : 0.0f;
        __syncthreads();
        bh[y] += ah;
        bv[y] += av;
        __syncthreads();
    }
    D[r * NBY + y] = make_float2(bh[y], bv[y]);
}

// Pass 5: inclusive x-scan per column + finalize.
__global__ void __launch_bounds__(256) scan_cols_finalize(
    const float2* __restrict__ D,
    const float* __restrict__ init_h,
    const float* __restrict__ init_v,
    float* __restrict__ out) {
    __shared__ float bh[NBX];
    __shared__ float bv[NBX];
    int y = blockIdx.x;
    int x = threadIdx.x;
    float2 t = D[x * NBY + y];
    bh[x] = t.x;
    bv[x] = t.y;
    __syncthreads();
    for (int off = 1; off < NBX; off <<= 1) {
        float ah = (x >= off) ? bh[x - off] : 0.0f;
        float av = (x >= off) ? bv[x - off] : 0.0f;
        __syncthreads();
        bh[x] += ah;
        bv[x] += av;
        __syncthreads();
    }
    int idx = x * NBY + y;
    float H = fmaf(bh[x], INV_H, init_h[idx]);
    float V = fmaf(bv[x], INV_V, init_v[idx]);
    float r = fmaxf(fabsf(H), fabsf(V));
    out[idx]            = r;
    out[idx + NMAP]     = H;
    out[idx + 2 * NMAP] = V;
}

extern "C" void kernel_launch(void* const* d_in, const int* in_sizes, int n_in,
                              void* d_out, int out_size, void* d_ws, size_t ws_size,
                              hipStream_t stream) {
    const float* pin_pos      = (const float*)d_in[0];
    const int*   netpin_start = (const int*)d_in[1];
    const int*   flat_netpin  = (const int*)d_in[2];
    const float* net_weights  = (const float*)d_in[3];
    const float* init_h       = (const float*)d_in[4];
    const float* init_v       = (const float*)d_in[5];
    float* out = (float*)d_out;

    int num_nets = in_sizes[3];
    int Np = (num_nets + 255) & ~255;

    // ws layout (~5.9 MB @100k nets):
    // [bbox4 Np*16][Dsub MAXCH*2*256*8][D NMAP*8][bucket 4*Np*4]
    // [chunks MAXCH*16][cbeg 512][ckc 512][gcount 512][gcursor 512][hdr 64]
    char* w = (char*)d_ws;
    size_t o = 0;
    float4*   bbox4   = (float4*)(w + o);   o += (size_t)Np * 16;
    float2*   Dsub    = (float2*)(w + o);   o += (size_t)MAXCH * 2 * NBY * 8;
    float2*   D       = (float2*)(w + o);   o += (size_t)NMAP * 8;
    int*      bucket  = (int*)(w + o);      o += (size_t)4 * Np * 4;
    int4*     chunks  = (int4*)(w + o);     o += (size_t)MAXCH * 16;
    int*      cbeg    = (int*)(w + o);      o += 512;
    int*      ckc     = (int*)(w + o);      o += 512;
    unsigned* gcount  = (unsigned*)(w + o); o += 512;
    unsigned* gcursor = (unsigned*)(w + o); o += 512;
    int*      hdr     = (int*)(w + o);      o += 64;

    net_bbox<<<Np / 32, 256, 0, stream>>>(pin_pos, netpin_start, flat_netpin,
                                          bbox4, gcount, num_nets, Np);
    bucket_count<<<Np / 256, 256, 0, stream>>>(bbox4, gcount, Np);
    plan_build<<<1, 128, 0, stream>>>(gcount, gcursor, chunks, cbeg, ckc, hdr);
    bucket_place<<<Np / 256, 256, 0, stream>>>(bbox4, gcursor, bucket, Np);
    chunk_build<<<MAXCH, 256, 0, stream>>>(bbox4, net_weights, bucket,
                                           chunks, hdr, Dsub);
    fold_rows<<<NBX, 256, 0, stream>>>(Dsub, cbeg, ckc, D);
    scan_cols_finalize<<<NBY, 256, 0, stream>>>(D, init_h, init_v, out);
}